// Round 4
// baseline (730.320 us; speedup 1.0000x reference)
//
#include <hip/hip_runtime.h>

// LSPD_43404939493531: bidirectional 2-layer GRU (B=512,T=512,U=32) + BN folds + dense head.
// R9: R8 with the one-line compile fix (cvt_pkrtz returns __fp16x2, capture via auto+bit_cast).
//     GRU recurrence on the MATRIX pipe. R7 counters: gru1 VALUBusy 68%, 0 LDS, 7% HBM,
//     1 wave/SIMD, ~158 VALU inst/step (96 scalar FMAs for a 96x32 matvec) -> issue-bound.
//     Structure: one wave = 16 batch rows; gates = mfma_f32_16x16x32_f16, D(g=96 gates via
//     6 row-tiles, col=16 batches). gru1: 12 MFMAs/step (6 x-proj from Wp + 6 recurrent from U,
//     z/r chained through the C operand; ih/rh kept separate for reset_after semantics).
//     gru0: 6 MFMAs/step + 6 float4 tab-gathers (x-part) in C-layout.
//     Layout safety: C/D mapping is the HW-verified col=lane&15,row=(lane>>4)*4+reg. The K-slot
//     mapping of A/B only needs A<->B consistency: B (h,x) is routed through a fixed
//     permlane32/16-swap network, and the slot->channel map is CALIBRATED once by pushing index
//     payloads through the same network; A-tiles (U/Wp) are loaded via the calibrated map, so
//     any permlane-semantics deviation cancels. f16 operands + f32 MFMA accum + f32 state h.
//     h state lives in registers in C-layout; stores are 2x dwordx4 per lane (all 64 lanes);
//     x float4-prefetch 4-deep (L3-resident), gru0 gathers 2-deep with idx 4-deep.

#define Bsz 512
#define Tsz 512

typedef unsigned uintv2 __attribute__((ext_vector_type(2)));
typedef _Float16 half8 __attribute__((ext_vector_type(8)));
typedef float f32x4 __attribute__((ext_vector_type(4)));

union H8 { unsigned u[4]; half8 h; };

__device__ __forceinline__ float sigmoid_f(float x) {
    return __builtin_amdgcn_rcpf(1.0f + __expf(-x));
}

// ---- cross-lane swaps (VALU pipe), two-result form ----
__device__ __forceinline__ uintv2 p16(unsigned a, unsigned b) {
#if __has_builtin(__builtin_amdgcn_permlane16_swap)
    return __builtin_amdgcn_permlane16_swap(a, b, false, false);
#else
    asm("v_permlane16_swap_b32 %0, %1" : "+v"(a), "+v"(b));
    uintv2 r; r.x = a; r.y = b; return r;
#endif
}
__device__ __forceinline__ uintv2 p32(unsigned a, unsigned b) {
#if __has_builtin(__builtin_amdgcn_permlane32_swap)
    return __builtin_amdgcn_permlane32_swap(a, b, false, false);
#else
    asm("v_permlane32_swap_b32 %0, %1" : "+v"(a), "+v"(b));
    uintv2 r; r.x = a; r.y = b; return r;
#endif
}

// Fixed routing network: 4 packed words (2 ch each, C-layout) -> 4 B-fragment words.
// Used identically for calibration payloads and runtime data -> semantics-agnostic.
__device__ __forceinline__ void route4(unsigned P0, unsigned P1, unsigned P2, unsigned P3,
                                       unsigned& W0, unsigned& W1, unsigned& W2, unsigned& W3)
{
    uintv2 m = p32(P0, P2);
    uintv2 a = p16(m.x, m.y);
    uintv2 n = p32(P1, P3);
    uintv2 c = p16(n.x, n.y);
    W0 = a.x; W2 = a.y; W1 = c.x; W3 = c.y;
}

__device__ __forceinline__ unsigned pk16(float a, float b) {
    auto h = __builtin_amdgcn_cvt_pkrtz(a, b);   // __fp16 ext_vector_type(2)
    return __builtin_bit_cast(unsigned, h);
}

__device__ __forceinline__ H8 make_B(float v0, float v1, float v2, float v3,
                                     float v4, float v5, float v6, float v7)
{
    unsigned P0 = pk16(v0, v1), P1 = pk16(v2, v3);
    unsigned P2 = pk16(v4, v5), P3 = pk16(v6, v7);
    H8 b;
    route4(P0, P1, P2, P3, b.u[0], b.u[1], b.u[2], b.u[3]);
    return b;
}

// calibrate: cs[e] = channel whose value lands in B-slot e (word e>>1, half e&1) for this lane
__device__ __forceinline__ void calib_slots(int lane, int cs[8]) {
    unsigned q = (unsigned)(lane >> 4) & 3u;
    unsigned c0 = 4u * q, c1 = 16u + 4u * q;
    unsigned P0 = c0 | ((c0 + 1u) << 16);
    unsigned P1 = (c0 + 2u) | ((c0 + 3u) << 16);
    unsigned P2 = c1 | ((c1 + 1u) << 16);
    unsigned P3 = (c1 + 2u) | ((c1 + 3u) << 16);
    unsigned W0, W1, W2, W3;
    route4(P0, P1, P2, P3, W0, W1, W2, W3);
    cs[0] = W0 & 0xffff; cs[1] = W0 >> 16;
    cs[2] = W1 & 0xffff; cs[3] = W1 >> 16;
    cs[4] = W2 & 0xffff; cs[5] = W2 >> 16;
    cs[6] = W3 & 0xffff; cs[7] = W3 >> 16;
}

// A-tile: row = lane&15 (gate row within tile), slot e multiplies B slot e -> load via cs[]
__device__ __forceinline__ H8 load_A(const float* __restrict__ M, const int cs[8], int gcol) {
    H8 a;
#pragma unroll
    for (int e = 0; e < 4; ++e)
        a.u[e] = pk16(M[cs[2 * e] * 96 + gcol], M[cs[2 * e + 1] * 96 + gcol]);
    return a;
}

__device__ __forceinline__ f32x4 mfma16(const H8& a, const H8& b, f32x4 c) {
    return __builtin_amdgcn_mfma_f32_16x16x32_f16(a.h, b.h, c, 0, 0, 0);
}

__device__ __forceinline__ float gate1(float az, float ar, float ah, float ai, float h) {
    float z = sigmoid_f(az);
    float r = sigmoid_f(ar);
    float hh = fmaxf(0.f, fmaf(r, ah, ai));
    return hh + z * (h - hh);
}

// ---------------- K1: argmax over D=128, one wave per (b,t), t-fastest ----------------
__global__ __launch_bounds__(256) void lspd_argmax(const float* __restrict__ x, int* __restrict__ idxT)
{
    int wv = threadIdx.x >> 6, lane = threadIdx.x & 63;
    long p = (long)blockIdx.x * 4 + wv;           // p = b*512 + t
    const float* xp = x + p * 128;
    float v0 = xp[lane];      int i0 = lane;
    float v1 = xp[64 + lane]; int i1 = 64 + lane;
    if (v1 > v0) { v0 = v1; i0 = i1; }            // ties keep lower index (first occurrence)
#pragma unroll
    for (int d = 1; d < 64; d <<= 1) {
        float ov = __shfl_xor(v0, d, 64);
        int   oi = __shfl_xor(i0, d, 64);
        if (ov > v0 || (ov == v0 && oi < i0)) { v0 = ov; i0 = oi; }
    }
    if (lane == 0) idxT[p] = i0;
}

// ---------------- K0: layer-0 input tables tab[i][g] = (emb@W0)[i][g] + b0_in[g] ----------------
__global__ __launch_bounds__(256) void lspd_tab(
    const float* __restrict__ emb, const float* __restrict__ Wl, const float* __restrict__ bl,
    const float* __restrict__ Wr, const float* __restrict__ br,
    float* __restrict__ tabL, float* __restrict__ tabR)
{
    int flat = blockIdx.x * 256 + threadIdx.x;    // 0..24575
    int dir = flat / 12288;
    int r = flat % 12288;
    int i = r / 96, g = r % 96;
    const float* W  = dir ? Wr : Wl;              // layer 0 at base
    const float* bb = dir ? br : bl;              // b[0][0] input bias at base
    float acc = bb[g];
#pragma unroll
    for (int k = 0; k < 32; ++k) acc = fmaf(emb[i * 32 + k], W[k * 96 + g], acc);
    (dir ? tabR : tabL)[r] = acc;
}

// ---------------- K2: layer-0 GRU (MFMA), 16 batch rows per wave ----------------
__global__ __launch_bounds__(64)
__attribute__((amdgpu_waves_per_eu(1, 1)))
void lspd_gru0(
    const int* __restrict__ idxT, const float* __restrict__ tabL, const float* __restrict__ tabR,
    const float* __restrict__ Ul, const float* __restrict__ Ur,
    const float* __restrict__ bl, const float* __restrict__ br,
    float* __restrict__ Lout, float* __restrict__ Rout)
{
    int bid = blockIdx.x;
    int dir = bid >> 5;
    int bg  = bid & 31;
    int lane = threadIdx.x;
    int rl = lane & 15;                 // B/C col = batch; A row = gate row
    int q  = lane >> 4;
    int b  = bg * 16 + rl;
    const float* U    = dir ? Ur : Ul;
    const float* tab  = dir ? tabR : tabL;
    const float* brec = (dir ? br : bl) + 96;     // layer-0 recurrent bias
    float* out        = dir ? Rout : Lout;

    int cs[8];
    calib_slots(lane, cs);

    // recurrent A tiles (gate G in {z,r,h}, channel half hf)
    H8 AUz0 = load_A(U, cs, 0  + rl), AUz1 = load_A(U, cs, 16 + rl);
    H8 AUr0 = load_A(U, cs, 32 + rl), AUr1 = load_A(U, cs, 48 + rl);
    H8 AUh0 = load_A(U, cs, 64 + rl), AUh1 = load_A(U, cs, 80 + rl);
    // recurrent-bias C fragments: value = brec[gate_off + hf*16 + 4q + reg]
    f32x4 BZ0 = *(const f32x4*)(brec + 0  + 4 * q);
    f32x4 BZ1 = *(const f32x4*)(brec + 16 + 4 * q);
    f32x4 BR0 = *(const f32x4*)(brec + 32 + 4 * q);
    f32x4 BR1 = *(const f32x4*)(brec + 48 + 4 * q);
    f32x4 BH0 = *(const f32x4*)(brec + 64 + 4 * q);
    f32x4 BH1 = *(const f32x4*)(brec + 80 + 4 * q);

    const int* idxrow = idxT + (long)b * Tsz;

#define TT0(s) (dir ? (Tsz - 2 - (s)) : (1 + (s)))
    // boundary zero row
    {
        long zb = ((long)(dir ? Tsz - 1 : 0) * Bsz + b) * 32;
        float4 z4 = make_float4(0.f, 0.f, 0.f, 0.f);
        *(float4*)(out + zb + 4 * q) = z4;
        *(float4*)(out + zb + 16 + 4 * q) = z4;
    }
    long ob = ((long)TT0(0) * Bsz + b) * 32;
    long ostride = (long)(dir ? -1 : 1) * Bsz * 32;

    // gather pipeline: sets GA (even steps), GB (odd steps), 2-deep; idx 4-deep
    float4 GAz0, GAz1, GAr0, GAr1, GAh0, GAh1;
    float4 GBz0, GBz1, GBr0, GBr1, GBh0, GBh1;
    {
        long ta = (long)idxrow[TT0(0)] * 96;
        GAz0 = *(const float4*)(tab + ta + 0  + 4 * q);
        GAz1 = *(const float4*)(tab + ta + 16 + 4 * q);
        GAr0 = *(const float4*)(tab + ta + 32 + 4 * q);
        GAr1 = *(const float4*)(tab + ta + 48 + 4 * q);
        GAh0 = *(const float4*)(tab + ta + 64 + 4 * q);
        GAh1 = *(const float4*)(tab + ta + 80 + 4 * q);
        long tb = (long)idxrow[TT0(1)] * 96;
        GBz0 = *(const float4*)(tab + tb + 0  + 4 * q);
        GBz1 = *(const float4*)(tab + tb + 16 + 4 * q);
        GBr0 = *(const float4*)(tab + tb + 32 + 4 * q);
        GBr1 = *(const float4*)(tab + tb + 48 + 4 * q);
        GBh0 = *(const float4*)(tab + tb + 64 + 4 * q);
        GBh1 = *(const float4*)(tab + tb + 80 + 4 * q);
    }
    int i0 = idxrow[TT0(2)];
    int i1 = idxrow[TT0(3)];
    int i2 = idxrow[TT0(4)];
    int i3 = idxrow[TT0(5)];

    float h0 = 0.f, h1 = 0.f, h2 = 0.f, h3 = 0.f, h4 = 0.f, h5 = 0.f, h6 = 0.f, h7 = 0.f;

#define STEP0(Gz0, Gz1, Gr0, Gr1, Gh0, Gh1, IREG, SINEXT)                      \
    {                                                                          \
        H8 Bh = make_B(h0, h1, h2, h3, h4, h5, h6, h7);                        \
        f32x4 Cz0 = mfma16(AUz0, Bh, BZ0);                                     \
        f32x4 Cz1 = mfma16(AUz1, Bh, BZ1);                                     \
        f32x4 Cr0 = mfma16(AUr0, Bh, BR0);                                     \
        f32x4 Cr1 = mfma16(AUr1, Bh, BR1);                                     \
        f32x4 Ch0 = mfma16(AUh0, Bh, BH0);                                     \
        f32x4 Ch1 = mfma16(AUh1, Bh, BH1);                                     \
        long tb2 = (long)IREG * 96;                                            \
        float4 nz0 = *(const float4*)(tab + tb2 + 0  + 4 * q);                 \
        float4 nz1 = *(const float4*)(tab + tb2 + 16 + 4 * q);                 \
        float4 nr0 = *(const float4*)(tab + tb2 + 32 + 4 * q);                 \
        float4 nr1 = *(const float4*)(tab + tb2 + 48 + 4 * q);                 \
        float4 nh0 = *(const float4*)(tab + tb2 + 64 + 4 * q);                 \
        float4 nh1 = *(const float4*)(tab + tb2 + 80 + 4 * q);                 \
        int sn = (SINEXT); if (sn > Tsz - 2) sn = Tsz - 2;                     \
        IREG = idxrow[TT0(sn)];                                                \
        h0 = gate1(Cz0.x + Gz0.x, Cr0.x + Gr0.x, Ch0.x, Gh0.x, h0);            \
        h1 = gate1(Cz0.y + Gz0.y, Cr0.y + Gr0.y, Ch0.y, Gh0.y, h1);            \
        h2 = gate1(Cz0.z + Gz0.z, Cr0.z + Gr0.z, Ch0.z, Gh0.z, h2);            \
        h3 = gate1(Cz0.w + Gz0.w, Cr0.w + Gr0.w, Ch0.w, Gh0.w, h3);            \
        h4 = gate1(Cz1.x + Gz1.x, Cr1.x + Gr1.x, Ch1.x, Gh1.x, h4);            \
        h5 = gate1(Cz1.y + Gz1.y, Cr1.y + Gr1.y, Ch1.y, Gh1.y, h5);            \
        h6 = gate1(Cz1.z + Gz1.z, Cr1.z + Gr1.z, Ch1.z, Gh1.z, h6);            \
        h7 = gate1(Cz1.w + Gz1.w, Cr1.w + Gr1.w, Ch1.w, Gh1.w, h7);            \
        *(float4*)(out + ob + 4 * q) = make_float4(h0, h1, h2, h3);            \
        *(float4*)(out + ob + 16 + 4 * q) = make_float4(h4, h5, h6, h7);       \
        ob += ostride;                                                         \
        Gz0 = nz0; Gz1 = nz1; Gr0 = nr0; Gr1 = nr1; Gh0 = nh0; Gh1 = nh1;      \
    }

    for (int sb = 0; sb < 508; sb += 4) {
        STEP0(GAz0, GAz1, GAr0, GAr1, GAh0, GAh1, i0, sb + 6);
        STEP0(GBz0, GBz1, GBr0, GBr1, GBh0, GBh1, i1, sb + 7);
        STEP0(GAz0, GAz1, GAr0, GAr1, GAh0, GAh1, i2, sb + 8);
        STEP0(GBz0, GBz1, GBr0, GBr1, GBh0, GBh1, i3, sb + 9);
    }
    STEP0(GAz0, GAz1, GAr0, GAr1, GAh0, GAh1, i0, 510);
    STEP0(GBz0, GBz1, GBr0, GBr1, GBh0, GBh1, i1, 510);
    STEP0(GAz0, GAz1, GAr0, GAr1, GAh0, GAh1, i2, 510);
#undef STEP0
#undef TT0
}

// ---------------- K3/K5: per-channel sum & sumsq of (L+R) ----------------
__global__ __launch_bounds__(256) void lspd_stats(
    const float* __restrict__ A, const float* __restrict__ Bv, float* __restrict__ part)
{
    __shared__ float sS[256], sQ[256];
    int tid = threadIdx.x;
    size_t base = (size_t)blockIdx.x * 65536 + tid;
    float s = 0.f, q = 0.f;
    for (int i = 0; i < 256; ++i) {
        size_t ix = base + (size_t)i * 256;
        float v = A[ix] + Bv[ix];
        s += v; q = fmaf(v, v, q);
    }
    sS[tid] = s; sQ[tid] = q;
    __syncthreads();
    if (tid < 32) {
        float S = 0.f, Q = 0.f;
        for (int j = 0; j < 8; ++j) { S += sS[tid + 32 * j]; Q += sQ[tid + 32 * j]; }
        part[blockIdx.x * 64 + tid] = S;
        part[blockIdx.x * 64 + 32 + tid] = Q;
    }
}

// ---------------- K3b: fold layer-0 BN into layer-1 input weights ----------------
__global__ __launch_bounds__(256) void lspd_fold1(
    const float* __restrict__ part, const float* __restrict__ g0, const float* __restrict__ be0,
    const float* __restrict__ Wl, const float* __restrict__ Wr,
    const float* __restrict__ bl, const float* __restrict__ br,
    float* __restrict__ WpL, float* __restrict__ WpR,
    float* __restrict__ b4L, float* __restrict__ b4R)
{
    __shared__ float sc[32], tc[32];
    int tid = threadIdx.x;
    if (tid < 32) {
        float S = 0.f, Q = 0.f;
        for (int p = 0; p < 128; ++p) { S += part[p * 64 + tid]; Q += part[p * 64 + 32 + tid]; }
        const float invN = 1.0f / 262144.0f;
        float m = S * invN;
        float v = Q * invN - m * m;
        float s = g0[tid] * __builtin_amdgcn_rsqf(v + 1e-3f);
        sc[tid] = s; tc[tid] = be0[tid] - s * m;
    }
    __syncthreads();
    for (int idx = tid; idx < 6144; idx += 256) {
        int dir = idx / 3072, e = idx % 3072, k = e / 96, g = e % 96;
        const float* W1 = (dir ? Wr : Wl) + 3072;      // layer 1
        (dir ? WpR : WpL)[e] = sc[k] * W1[k * 96 + g];
    }
    {
        int idx = tid;                                  // 256 entries exactly
        int dir = idx >> 7, slot = idx & 127, sub = slot >> 5, cc = slot & 31;
        const float* bb = (dir ? br : bl) + 192;        // layer-1: [0..95]=input, [96..191]=recurrent
        const float* W1 = (dir ? Wr : Wl) + 3072;
        float r;
        if (sub == 2) {
            r = bb[96 + 64 + cc];                       // rh: recurrent h-bias only
        } else {
            int g = (sub == 3) ? (64 + cc) : (sub * 32 + cc);
            float acc = bb[g];                          // input bias
            for (int k = 0; k < 32; ++k) acc = fmaf(tc[k], W1[k * 96 + g], acc);
            if (sub < 2) acc += bb[96 + g];             // z,r: + recurrent bias
            r = acc;
        }
        (dir ? b4R : b4L)[slot] = r;
    }
}

// ---------------- K4: layer-1 GRU (MFMA) with on-the-fly folded x-projection ----------------
__global__ __launch_bounds__(64)
__attribute__((amdgpu_waves_per_eu(1, 1)))
void lspd_gru1(
    const float* __restrict__ L0, const float* __restrict__ R0,
    const float* __restrict__ WpL, const float* __restrict__ WpR,
    const float* __restrict__ b4L, const float* __restrict__ b4R,
    const float* __restrict__ Ul1, const float* __restrict__ Ur1,
    float* __restrict__ Lout, float* __restrict__ Rout)
{
    int bid = blockIdx.x;
    int dir = bid >> 5;
    int bg  = bid & 31;
    int lane = threadIdx.x;
    int rl = lane & 15;
    int q  = lane >> 4;
    int b  = bg * 16 + rl;
    const float* U  = dir ? Ur1 : Ul1;
    const float* Wp = dir ? WpR : WpL;
    const float* b4 = dir ? b4R : b4L;
    float* out      = dir ? Rout : Lout;

    int cs[8];
    calib_slots(lane, cs);

    H8 AWz0 = load_A(Wp, cs, 0  + rl), AWz1 = load_A(Wp, cs, 16 + rl);
    H8 AWr0 = load_A(Wp, cs, 32 + rl), AWr1 = load_A(Wp, cs, 48 + rl);
    H8 AWh0 = load_A(Wp, cs, 64 + rl), AWh1 = load_A(Wp, cs, 80 + rl);
    H8 AUz0 = load_A(U, cs, 0  + rl),  AUz1 = load_A(U, cs, 16 + rl);
    H8 AUr0 = load_A(U, cs, 32 + rl),  AUr1 = load_A(U, cs, 48 + rl);
    H8 AUh0 = load_A(U, cs, 64 + rl),  AUh1 = load_A(U, cs, 80 + rl);
    // bias fragments: b4 = [z total(32) | r total(32) | rh rec-bias(32) | ih folded(32)]
    f32x4 BZ0 = *(const f32x4*)(b4 + 0   + 4 * q);
    f32x4 BZ1 = *(const f32x4*)(b4 + 16  + 4 * q);
    f32x4 BR0 = *(const f32x4*)(b4 + 32  + 4 * q);
    f32x4 BR1 = *(const f32x4*)(b4 + 48  + 4 * q);
    f32x4 BH0 = *(const f32x4*)(b4 + 64  + 4 * q);
    f32x4 BH1 = *(const f32x4*)(b4 + 80  + 4 * q);
    f32x4 BI0 = *(const f32x4*)(b4 + 96  + 4 * q);
    f32x4 BI1 = *(const f32x4*)(b4 + 112 + 4 * q);

#define XBASE(s) (((long)(dir ? (Tsz - 2 - (s)) : (1 + (s))) * Bsz + b) * 32)
    {
        long zb = ((long)(dir ? Tsz - 1 : 0) * Bsz + b) * 32;
        float4 z4 = make_float4(0.f, 0.f, 0.f, 0.f);
        *(float4*)(out + zb + 4 * q) = z4;
        *(float4*)(out + zb + 16 + 4 * q) = z4;
    }
    long ob = XBASE(0);
    long ostride = (long)(dir ? -1 : 1) * Bsz * 32;

    // x prefetch: 4 slots x (L lo, L hi, R lo, R hi)
    float4 la0, lb0, ra0, rb0, la1, lb1, ra1, rb1;
    float4 la2, lb2, ra2, rb2, la3, lb3, ra3, rb3;
    {
        long n0 = XBASE(0);
        la0 = *(const float4*)(L0 + n0 + 4 * q); lb0 = *(const float4*)(L0 + n0 + 16 + 4 * q);
        ra0 = *(const float4*)(R0 + n0 + 4 * q); rb0 = *(const float4*)(R0 + n0 + 16 + 4 * q);
        long n1 = XBASE(1);
        la1 = *(const float4*)(L0 + n1 + 4 * q); lb1 = *(const float4*)(L0 + n1 + 16 + 4 * q);
        ra1 = *(const float4*)(R0 + n1 + 4 * q); rb1 = *(const float4*)(R0 + n1 + 16 + 4 * q);
        long n2 = XBASE(2);
        la2 = *(const float4*)(L0 + n2 + 4 * q); lb2 = *(const float4*)(L0 + n2 + 16 + 4 * q);
        ra2 = *(const float4*)(R0 + n2 + 4 * q); rb2 = *(const float4*)(R0 + n2 + 16 + 4 * q);
        long n3 = XBASE(3);
        la3 = *(const float4*)(L0 + n3 + 4 * q); lb3 = *(const float4*)(L0 + n3 + 16 + 4 * q);
        ra3 = *(const float4*)(R0 + n3 + 4 * q); rb3 = *(const float4*)(R0 + n3 + 16 + 4 * q);
    }
    float h0 = 0.f, h1 = 0.f, h2 = 0.f, h3 = 0.f, h4 = 0.f, h5 = 0.f, h6 = 0.f, h7 = 0.f;

#define STEP1(XLA, XLB, XRA, XRB, SNEXT)                                       \
    {                                                                          \
        H8 Bx = make_B(XLA.x + XRA.x, XLA.y + XRA.y, XLA.z + XRA.z,            \
                       XLA.w + XRA.w, XLB.x + XRB.x, XLB.y + XRB.y,            \
                       XLB.z + XRB.z, XLB.w + XRB.w);                          \
        f32x4 Cz0 = mfma16(AWz0, Bx, BZ0);                                     \
        f32x4 Cz1 = mfma16(AWz1, Bx, BZ1);                                     \
        f32x4 Cr0 = mfma16(AWr0, Bx, BR0);                                     \
        f32x4 Cr1 = mfma16(AWr1, Bx, BR1);                                     \
        f32x4 Ci0 = mfma16(AWh0, Bx, BI0);                                     \
        f32x4 Ci1 = mfma16(AWh1, Bx, BI1);                                     \
        int sn = (SNEXT); if (sn > Tsz - 2) sn = Tsz - 2;                      \
        long nb = XBASE(sn);                                                   \
        XLA = *(const float4*)(L0 + nb + 4 * q);                               \
        XLB = *(const float4*)(L0 + nb + 16 + 4 * q);                          \
        XRA = *(const float4*)(R0 + nb + 4 * q);                               \
        XRB = *(const float4*)(R0 + nb + 16 + 4 * q);                          \
        H8 Bh = make_B(h0, h1, h2, h3, h4, h5, h6, h7);                        \
        Cz0 = mfma16(AUz0, Bh, Cz0);                                           \
        Cz1 = mfma16(AUz1, Bh, Cz1);                                           \
        Cr0 = mfma16(AUr0, Bh, Cr0);                                           \
        Cr1 = mfma16(AUr1, Bh, Cr1);                                           \
        f32x4 Ch0 = mfma16(AUh0, Bh, BH0);                                     \
        f32x4 Ch1 = mfma16(AUh1, Bh, BH1);                                     \
        h0 = gate1(Cz0.x, Cr0.x, Ch0.x, Ci0.x, h0);                            \
        h1 = gate1(Cz0.y, Cr0.y, Ch0.y, Ci0.y, h1);                            \
        h2 = gate1(Cz0.z, Cr0.z, Ch0.z, Ci0.z, h2);                            \
        h3 = gate1(Cz0.w, Cr0.w, Ch0.w, Ci0.w, h3);                            \
        h4 = gate1(Cz1.x, Cr1.x, Ch1.x, Ci1.x, h4);                            \
        h5 = gate1(Cz1.y, Cr1.y, Ch1.y, Ci1.y, h5);                            \
        h6 = gate1(Cz1.z, Cr1.z, Ch1.z, Ci1.z, h6);                            \
        h7 = gate1(Cz1.w, Cr1.w, Ch1.w, Ci1.w, h7);                            \
        *(float4*)(out + ob + 4 * q) = make_float4(h0, h1, h2, h3);            \
        *(float4*)(out + ob + 16 + 4 * q) = make_float4(h4, h5, h6, h7);       \
        ob += ostride;                                                         \
    }

    for (int sb = 0; sb < 508; sb += 4) {
        STEP1(la0, lb0, ra0, rb0, sb + 4);
        STEP1(la1, lb1, ra1, rb1, sb + 5);
        STEP1(la2, lb2, ra2, rb2, sb + 6);
        STEP1(la3, lb3, ra3, rb3, sb + 7);
    }
    STEP1(la0, lb0, ra0, rb0, 510);
    STEP1(la1, lb1, ra1, rb1, 510);
    STEP1(la2, lb2, ra2, rb2, 510);
#undef STEP1
#undef XBASE
}

// ---------------- K5b: fold layer-1 BN into dense-1 weights ----------------
__global__ __launch_bounds__(256) void lspd_fold2(
    const float* __restrict__ part, const float* __restrict__ g1, const float* __restrict__ be1,
    const float* __restrict__ Wd1, const float* __restrict__ bd1,
    float* __restrict__ Wdp, float* __restrict__ bdp)
{
    __shared__ float sc[32], tc[32];
    int tid = threadIdx.x;
    if (tid < 32) {
        float S = 0.f, Q = 0.f;
        for (int p = 0; p < 128; ++p) { S += part[p * 64 + tid]; Q += part[p * 64 + 32 + tid]; }
        const float invN = 1.0f / 262144.0f;
        float m = S * invN;
        float v = Q * invN - m * m;
        float s = g1[tid] * __builtin_amdgcn_rsqf(v + 1e-3f);
        sc[tid] = s; tc[tid] = be1[tid] - s * m;
    }
    __syncthreads();
    for (int idx = tid; idx < 1024; idx += 256) {
        int k = idx >> 5;
        Wdp[idx] = sc[k] * Wd1[idx];
    }
    if (tid < 32) {
        float acc = bd1[tid];
        for (int k = 0; k < 32; ++k) acc = fmaf(tc[k], Wd1[k * 32 + tid], acc);
        bdp[tid] = acc;
    }
}

// ---------------- K6: dense + per-t batch BN + classifier + softmax; one block per t ----------------
__global__ __launch_bounds__(512) void lspd_final(
    const float* __restrict__ L1a, const float* __restrict__ R1a,
    const float* __restrict__ Wdp, const float* __restrict__ bdp,
    const float* __restrict__ dg, const float* __restrict__ db,
    const float* __restrict__ Wf, const float* __restrict__ bfv,
    float* __restrict__ outp)
{
    __shared__ alignas(16) float sW[1024];
    __shared__ float sb[32], sWf[352], sbf[16], sS[32], sT[32];
    __shared__ float redS[8][32], redQ[8][32];
    int tid = threadIdx.x, t = blockIdx.x;
    for (int i = tid; i < 1024; i += 512) sW[i] = Wdp[i];
    if (tid < 32)  sb[tid] = bdp[tid];
    if (tid < 352) sWf[tid] = Wf[tid];
    if (tid < 11)  sbf[tid] = bfv[tid];
    __syncthreads();

    size_t base = ((size_t)t * Bsz + tid) * 32;
    float xv[32];
#pragma unroll
    for (int c2 = 0; c2 < 32; c2 += 4) {
        float4 a = *(const float4*)(L1a + base + c2);
        float4 b = *(const float4*)(R1a + base + c2);
        xv[c2 + 0] = a.x + b.x; xv[c2 + 1] = a.y + b.y;
        xv[c2 + 2] = a.z + b.z; xv[c2 + 3] = a.w + b.w;
    }
    float o[32];
#pragma unroll
    for (int g = 0; g < 32; ++g) o[g] = sb[g];
#pragma unroll
    for (int k = 0; k < 32; ++k) {
        float xk = xv[k];
#pragma unroll
        for (int g4 = 0; g4 < 8; ++g4) {
            float4 w = *(const float4*)(sW + k * 32 + g4 * 4);   // same-address LDS broadcast
            o[g4 * 4 + 0] = fmaf(xk, w.x, o[g4 * 4 + 0]);
            o[g4 * 4 + 1] = fmaf(xk, w.y, o[g4 * 4 + 1]);
            o[g4 * 4 + 2] = fmaf(xk, w.z, o[g4 * 4 + 2]);
            o[g4 * 4 + 3] = fmaf(xk, w.w, o[g4 * 4 + 3]);
        }
    }
#pragma unroll
    for (int g = 0; g < 32; ++g) o[g] = fmaxf(o[g], 0.f);

    // per-(t,channel) stats over batch (within block)
    int wv = tid >> 6, lane = tid & 63;
    for (int g = 0; g < 32; ++g) {
        float s = o[g], q = o[g] * o[g];
        for (int d = 1; d < 64; d <<= 1) {
            s += __shfl_xor(s, d, 64);
            q += __shfl_xor(q, d, 64);
        }
        if (lane == 0) { redS[wv][g] = s; redQ[wv][g] = q; }
    }
    __syncthreads();
    if (tid < 32) {
        float S = 0.f, Q = 0.f;
        for (int w2 = 0; w2 < 8; ++w2) { S += redS[w2][tid]; Q += redQ[w2][tid]; }
        float m = S * (1.0f / 512.0f);
        float v = Q * (1.0f / 512.0f) - m * m;
        float s = dg[tid] * __builtin_amdgcn_rsqf(v + 1e-3f);
        sS[tid] = s; sT[tid] = db[tid] - s * m;
    }
    __syncthreads();

    float lg[11];
#pragma unroll
    for (int n = 0; n < 11; ++n) lg[n] = sbf[n];
#pragma unroll
    for (int g = 0; g < 32; ++g) {
        float no = fmaf(o[g], sS[g], sT[g]);
#pragma unroll
        for (int n = 0; n < 11; ++n) lg[n] = fmaf(no, sWf[g * 11 + n], lg[n]);
    }
    float mx = lg[0];
#pragma unroll
    for (int n = 1; n < 11; ++n) mx = fmaxf(mx, lg[n]);
    float sum = 0.f;
#pragma unroll
    for (int n = 0; n < 11; ++n) { lg[n] = __expf(lg[n] - mx); sum += lg[n]; }
    float inv = __builtin_amdgcn_rcpf(sum);
    float* op = outp + ((size_t)tid * Tsz + t) * 11;
#pragma unroll
    for (int n = 0; n < 11; ++n) op[n] = lg[n] * inv;
}

extern "C" void kernel_launch(void* const* d_in, const int* in_sizes, int n_in,
                              void* d_out, int out_size, void* d_ws, size_t ws_size,
                              hipStream_t stream)
{
    (void)in_sizes; (void)n_in; (void)out_size; (void)ws_size;
    const float* x   = (const float*)d_in[0];
    const float* emb = (const float*)d_in[1];
    const float* Wl  = (const float*)d_in[2];
    const float* Ul  = (const float*)d_in[3];
    const float* bl  = (const float*)d_in[4];
    const float* Wr  = (const float*)d_in[5];
    const float* Ur  = (const float*)d_in[6];
    const float* br  = (const float*)d_in[7];
    const float* bng = (const float*)d_in[8];
    const float* bnb = (const float*)d_in[9];
    const float* Wd  = (const float*)d_in[10];
    const float* bd  = (const float*)d_in[11];
    const float* dg  = (const float*)d_in[12];
    const float* db  = (const float*)d_in[13];
    const float* Wf  = (const float*)d_in[14];
    const float* bf  = (const float*)d_in[15];
    float* out = (float*)d_out;

    float* ws = (float*)d_ws;
    float* L0 = ws;
    float* R0 = L0 + 8388608;
    float* L1 = R0 + 8388608;
    float* R1 = L1 + 8388608;
    float* rest = R1 + 8388608;
    int* idxT   = (int*)rest;            // 262144 ints
    float* tabL = rest + 262144;
    float* tabR = tabL + 12288;
    float* part1 = tabR + 12288;         // 8192
    float* part2 = part1 + 8192;         // 8192
    float* WpL = part2 + 8192;           // 3072
    float* WpR = WpL + 3072;
    float* b4L = WpR + 3072;             // 128
    float* b4R = b4L + 128;
    float* Wdp = b4R + 128;              // 1024
    float* bdp = Wdp + 1024;             // 32

    lspd_argmax<<<65536, 256, 0, stream>>>(x, idxT);
    lspd_tab<<<96, 256, 0, stream>>>(emb, Wl, bl, Wr, br, tabL, tabR);
    lspd_gru0<<<64, 64, 0, stream>>>(idxT, tabL, tabR, Ul, Ur, bl, br, L0, R0);
    lspd_stats<<<128, 256, 0, stream>>>(L0, R0, part1);
    lspd_fold1<<<1, 256, 0, stream>>>(part1, bng, bnb, Wl, Wr, bl, br, WpL, WpR, b4L, b4R);
    lspd_gru1<<<64, 64, 0, stream>>>(L0, R0, WpL, WpR, b4L, b4R, Ul + 3072, Ur + 3072, L1, R1);
    lspd_stats<<<128, 256, 0, stream>>>(L1, R1, part2);
    lspd_fold2<<<1, 256, 0, stream>>>(part2, bng + 32, bnb + 32, Wd + 1024, bd + 32, Wdp, bdp);
    lspd_final<<<512, 512, 0, stream>>>(L1, R1, Wdp, bdp, dg + 32, db + 32, Wf, bf, out);
}